// Round 1
// 1004.170 us; speedup vs baseline: 1.0635x; 1.0635x over previous
//
#include <hip/hip_runtime.h>
#include <hip/hip_bf16.h>

typedef _Float16 f16;
typedef f16 f16x2 __attribute__((ext_vector_type(2)));
typedef f16 f16x8 __attribute__((ext_vector_type(8)));
typedef float f32x4 __attribute__((ext_vector_type(4)));

__device__ __forceinline__ float dot2acc(f16x2 a, f16x2 b, float c) {
    return __builtin_amdgcn_fdot2(a, b, c, false);
}
__device__ __forceinline__ float sigmoid_f(float x) {
    return __builtin_amdgcn_rcpf(1.f + __expf(-x));
}
__device__ __forceinline__ float tanh_f(float x) {
    return 1.f - 2.f * __builtin_amdgcn_rcpf(__expf(2.f * x) + 1.f);
}
// quad-lane DPP shuffle (pure VALU; keeps the LDS pipe free)
template <int CTRL>
__device__ __forceinline__ float dppx(float x) {
    return __builtin_bit_cast(float,
        __builtin_amdgcn_mov_dpp(__builtin_bit_cast(int, x), CTRL, 0xF, 0xF, true));
}
#define DPP_XOR1 0xB1  // quad_perm [1,0,3,2]
#define DPP_XOR2 0x4E  // quad_perm [2,3,0,1]

// ------------------------------------------------- fused weight f32->f16 convert
__global__ __launch_bounds__(256) void cvt_weights_kernel(
    const float* __restrict__ wp, const float* __restrict__ wia, const float* __restrict__ wha,
    const float* __restrict__ wib, const float* __restrict__ whb, const float* __restrict__ wb,
    f16* __restrict__ o_wp, f16* __restrict__ o_wia, f16* __restrict__ o_wha,
    f16* __restrict__ o_wib, f16* __restrict__ o_whb, f16* __restrict__ o_wb)
{
    int i = blockIdx.x * 256 + threadIdx.x;
    if (i >= 221248) return;
    const float* s; f16* d; int off;
    if      (i < 8192)   { s = wp;  d = o_wp;  off = i; }
    else if (i < 57344)  { s = wia; d = o_wia; off = i - 8192; }
    else if (i < 106496) { s = wha; d = o_wha; off = i - 57344; }
    else if (i < 155648) { s = wib; d = o_wib; off = i - 106496; }
    else if (i < 204800) { s = whb; d = o_whb; off = i - 155648; }
    else                 { s = wb;  d = o_wb;  off = i - 204800; }
    float4 f = ((const float4*)s)[off];
    f16x2 p0; p0.x = (f16)f.x; p0.y = (f16)f.y;
    f16x2 p1; p1.x = (f16)f.z; p1.y = (f16)f.w;
    ((f16x2*)d)[off * 2]     = p0;
    ((f16x2*)d)[off * 2 + 1] = p1;
}

// ---------------------------------------------------------------- MFMA GEMM
#define BM 128
#define BN 128
#define BKC 64
#define LPAD 8

template <int KT, int NOUT, int EPI, bool CVTA, int BSPLIT>
__global__ __launch_bounds__(256) void gemm_kernel(
    const void* __restrict__ Araw, const f16* __restrict__ B,
    const float* __restrict__ bias, const float* __restrict__ bias2,
    f16* __restrict__ out16, const f16* __restrict__ xp16)
{
    __shared__ __align__(16) f16 As[BM][BKC + LPAD];
    __shared__ __align__(16) f16 Bs[BN][BKC + LPAD];
    int tid = threadIdx.x;
    int m0 = blockIdx.x * BM, n0 = blockIdx.y * BN;
    int wave = tid >> 6, lane = tid & 63;
    int wm = (wave & 1) * 64, wn = (wave >> 1) * 64;
    int quad = lane >> 4, l16 = lane & 15;

    f32x4 acc[4][4] = {};

    for (int kc = 0; kc < KT / BKC; ++kc) {
        __syncthreads();
#pragma unroll
        for (int i = 0; i < 4; ++i) {
            int idx = i * 256 + tid;
            int row = idx >> 3, c8 = idx & 7;
            if (CVTA) {
                const float* A32 = (const float*)Araw;
                const float* src = A32 + (size_t)(m0 + row) * KT + kc * BKC + c8 * 8;
                float4 fa = *(const float4*)src;
                float4 fb = *(const float4*)(src + 4);
                f16x8 h8;
                h8[0] = (f16)fa.x; h8[1] = (f16)fa.y; h8[2] = (f16)fa.z; h8[3] = (f16)fa.w;
                h8[4] = (f16)fb.x; h8[5] = (f16)fb.y; h8[6] = (f16)fb.z; h8[7] = (f16)fb.w;
                *(f16x8*)&As[row][c8 * 8] = h8;
            } else {
                const f16* A16 = (const f16*)Araw;
                uint4 va = *(const uint4*)(A16 + (size_t)(m0 + row) * KT + kc * BKC + c8 * 8);
                *(uint4*)&As[row][c8 * 8] = va;
            }
            uint4 vb = *(const uint4*)(B + (size_t)(n0 + row) * KT + kc * BKC + c8 * 8);
            *(uint4*)&Bs[row][c8 * 8] = vb;
        }
        __syncthreads();
#pragma unroll
        for (int kk = 0; kk < 2; ++kk) {
            f16x8 af[4], bf[4];
#pragma unroll
            for (int i = 0; i < 4; ++i) {
                af[i] = *(const f16x8*)&As[wm + i * 16 + l16][kk * 32 + quad * 8];
                bf[i] = *(const f16x8*)&Bs[wn + i * 16 + l16][kk * 32 + quad * 8];
            }
#pragma unroll
            for (int mi = 0; mi < 4; ++mi)
#pragma unroll
                for (int ni = 0; ni < 4; ++ni)
                    acc[mi][ni] = __builtin_amdgcn_mfma_f32_16x16x32_f16(af[mi], bf[ni], acc[mi][ni], 0, 0, 0);
        }
    }

#pragma unroll
    for (int ni = 0; ni < 4; ++ni) {
        int col = n0 + wn + ni * 16 + l16;
        float bv = (col < BSPLIT) ? bias[col] : bias2[col - BSPLIT];
#pragma unroll
        for (int mi = 0; mi < 4; ++mi) {
#pragma unroll
            for (int r = 0; r < 4; ++r) {
                int row = m0 + wm + mi * 16 + quad * 4 + r;
                float val = acc[mi][ni][r] + bv;
                if (EPI == 2) {
                    float tb = tanh_f(val);
                    float xpv = (float)xp16[(size_t)row * NOUT + col];
                    out16[(size_t)row * NOUT + col] = (f16)(tb * xpv);
                } else {
                    out16[(size_t)row * NOUT + col] = (f16)val;
                }
            }
        }
    }
}

// ---------------------------------------------------------------- GRU recurrence
// 256 blocks (1/CU): blockIdx>>7 = GRU (0=a,1=b), &127 = batch. 1024 threads
// (16 waves = 4 waves/EU) -> 128-VGPR budget; per-thread weights cut to 96 regs
// so they stay in ARCH VGPRs (round-6 theory: 84 arch + 128 AGPR-parked weights
// cost a v_accvgpr_read per dot2 -> the 2x VALU inflation in rocprof).
// Thread t = (j = t>>2, kp = t&3): owns rows {j, j+256, j+512} = r,z,n of the
// SAME h-index over k-chunk kp (64 h-elems) -> after the quad DPP butterfly all
// 4 lanes hold complete r/z/n partial sums for j, so the gate is computed
// in-register with NO hw[] LDS exchange and only ONE barrier per timestep.
// Scores are deferred: both GRUs store h16 to global; a tiny GEMV kernel does
// scores = xa @ Wa^T afterwards (removes the serial shfl chain from the loop).
#define XWS 1536

__global__ __launch_bounds__(1024)
__attribute__((amdgpu_waves_per_eu(4, 4)))
void rnn_kernel(
    const f16* __restrict__ xw_cat,
    const f16* __restrict__ whha, const f16* __restrict__ whhb,
    const float* __restrict__ bhha, const float* __restrict__ bhhb,
    f16* __restrict__ xa16, f16* __restrict__ xb16)
{
    int g = blockIdx.x >> 7, b = blockIdx.x & 127;
    int t = threadIdx.x;
    int kp = t & 3;           // k-chunk: h-elems [kp*64, kp*64+64)
    int j  = t >> 2;          // h index 0..255

    const f16* whh = g ? whhb : whha;
    const float* bhh = g ? bhhb : bhha;
    const f16* xw = xw_cat + (size_t)b * 512 * XWS + 768 * g;
    f16* hout = (g ? xb16 : xa16) + (size_t)b * 512 * 256;

    // weights: 3 rows (r,z,n of j) x 64 h-elems of chunk kp = 96 f16x2 = 96 VGPRs
    unsigned int w[96];
#pragma unroll
    for (int r = 0; r < 3; ++r) {
        const f16* src = whh + (size_t)(j + 256 * r) * 256 + kp * 64;
#pragma unroll
        for (int b8 = 0; b8 < 8; ++b8) {
            uint4 u = *(const uint4*)(src + b8 * 8);
            w[r * 32 + b8 * 4 + 0] = u.x;
            w[r * 32 + b8 * 4 + 1] = u.y;
            w[r * 32 + b8 * 4 + 2] = u.z;
            w[r * 32 + b8 * 4 + 3] = u.w;
        }
    }
#pragma unroll
    for (int i = 0; i < 96; ++i) asm volatile("" : "+v"(w[i]));  // pin in VGPRs

    float br = bhh[j];
    float bz = bhh[j + 256];
    float bn = bhh[j + 512];

    // h double buffer: chunk c (64 f16 = 128B) at f16 offset c*72 (144B stride
    // -> the 4 per-wave broadcast addresses land on disjoint bank groups)
    __shared__ __align__(16) f16 h2[2][288];

    if (t < 256) h2[0][(t >> 6) * 72 + (t & 63)] = (f16)0.f;
    __syncthreads();

    float hprev = 0.f;
    int cur = 0;
    // prefetch xW row for ts=0 (all 4 quad lanes load identical values)
    float xr = (float)xw[j];
    float xz = (float)xw[j + 256];
    float xn = (float)xw[j + 512];
    for (int ts = 0; ts < 512; ++ts) {
        // issue next timestep's xW loads early; dot phase hides the latency
        int tsn = (ts < 511) ? ts + 1 : ts;
        const f16* xwn = xw + (size_t)tsn * XWS;
        f16 nxr = xwn[j];
        f16 nxz = xwn[j + 256];
        f16 nxn = xwn[j + 512];

        // partial dots over chunk kp for rows j, j+256, j+512
        const f16* hb = &h2[cur][kp * 72];
        float a0 = 0.f, a1 = 0.f, a2 = 0.f;
#pragma unroll
        for (int i8 = 0; i8 < 8; ++i8) {
            uint4 u = *(const uint4*)(hb + i8 * 8);
            f16x2 p0 = __builtin_bit_cast(f16x2, u.x);
            f16x2 p1 = __builtin_bit_cast(f16x2, u.y);
            f16x2 p2 = __builtin_bit_cast(f16x2, u.z);
            f16x2 p3 = __builtin_bit_cast(f16x2, u.w);
            int kc = i8 * 4;
            a0 = dot2acc(p0, __builtin_bit_cast(f16x2, w[kc + 0]), a0);
            a0 = dot2acc(p1, __builtin_bit_cast(f16x2, w[kc + 1]), a0);
            a0 = dot2acc(p2, __builtin_bit_cast(f16x2, w[kc + 2]), a0);
            a0 = dot2acc(p3, __builtin_bit_cast(f16x2, w[kc + 3]), a0);
            a1 = dot2acc(p0, __builtin_bit_cast(f16x2, w[32 + kc + 0]), a1);
            a1 = dot2acc(p1, __builtin_bit_cast(f16x2, w[32 + kc + 1]), a1);
            a1 = dot2acc(p2, __builtin_bit_cast(f16x2, w[32 + kc + 2]), a1);
            a1 = dot2acc(p3, __builtin_bit_cast(f16x2, w[32 + kc + 3]), a1);
            a2 = dot2acc(p0, __builtin_bit_cast(f16x2, w[64 + kc + 0]), a2);
            a2 = dot2acc(p1, __builtin_bit_cast(f16x2, w[64 + kc + 1]), a2);
            a2 = dot2acc(p2, __builtin_bit_cast(f16x2, w[64 + kc + 2]), a2);
            a2 = dot2acc(p3, __builtin_bit_cast(f16x2, w[64 + kc + 3]), a2);
        }
        // quad butterfly: all 4 lanes end with the full sums (bit-identical)
        a0 += dppx<DPP_XOR1>(a0); a0 += dppx<DPP_XOR2>(a0);
        a1 += dppx<DPP_XOR1>(a1); a1 += dppx<DPP_XOR2>(a1);
        a2 += dppx<DPP_XOR1>(a2); a2 += dppx<DPP_XOR2>(a2);

        // gate math, duplicated across the quad (no LDS exchange, no barrier)
        float r = sigmoid_f(xr + a0 + br);
        float z = sigmoid_f(xz + a1 + bz);
        float n = tanh_f(xn + r * (a2 + bn));
        float hnew = z * (hprev - n) + n;   // (1-z)*n + z*h
        hprev = hnew;
        xr = (float)nxr; xz = (float)nxz; xn = (float)nxn;

        f16 h16 = (f16)hnew;
        if (kp == 0) {
            h2[cur ^ 1][(j >> 6) * 72 + (j & 63)] = h16;
            hout[(size_t)ts * 256 + j] = h16;
        }
        __syncthreads();   // h(t+1) visible for next dot phase
        cur ^= 1;
    }
}

// ---------------------------------------------------------------- scores GEMV
// scores[b,t] = xa[b,t,:] . Wa   (deferred from the recurrence loop)
__global__ __launch_bounds__(256) void scores_kernel(
    const f16* __restrict__ xa16, const float* __restrict__ Wa, float* __restrict__ scores)
{
    int b = blockIdx.x;          // 128 blocks
    int t = threadIdx.x;         // 4 waves
    int wv = t >> 6, l = t & 63;
    float wa0 = Wa[l * 4 + 0];
    float wa1 = Wa[l * 4 + 1];
    float wa2 = Wa[l * 4 + 2];
    float wa3 = Wa[l * 4 + 3];
    const f16* base = xa16 + (size_t)b * 512 * 256;
    for (int row = wv; row < 512; row += 4) {
        const f16* rp = base + (size_t)row * 256 + l * 4;
        uint2 u = *(const uint2*)rp;
        f16x2 p0 = __builtin_bit_cast(f16x2, u.x);
        f16x2 p1 = __builtin_bit_cast(f16x2, u.y);
        float s = (float)p0.x * wa0 + (float)p0.y * wa1
                + (float)p1.x * wa2 + (float)p1.y * wa3;
#pragma unroll
        for (int off = 32; off; off >>= 1) s += __shfl_xor(s, off);
        if (l == 0) scores[b * 512 + row] = s;
    }
}

// ---------------------------------------------------------------- attention
// Running-scan prefix softmax. Grid (128 batches, 2 h-halves) x 128 threads.
__global__ __launch_bounds__(128) void attn_kernel(
    const float* __restrict__ scores, const f16* __restrict__ v16, float* __restrict__ out)
{
    int b = blockIdx.x, tx = threadIdx.x;
    int h = blockIdx.y * 128 + tx;
    __shared__ float wle[512];
    __shared__ float red[2];

    float s0 = scores[b * 512 + tx];
    float s1 = scores[b * 512 + 128 + tx];
    float s2 = scores[b * 512 + 256 + tx];
    float s3 = scores[b * 512 + 384 + tx];
    float m = fmaxf(fmaxf(s0, s1), fmaxf(s2, s3));
#pragma unroll
    for (int off = 32; off; off >>= 1) m = fmaxf(m, __shfl_down(m, off));
    if ((tx & 63) == 0) red[tx >> 6] = m;
    __syncthreads();
    m = fmaxf(red[0], red[1]);
    wle[tx]       = __expf(s0 - m);
    wle[tx + 128] = __expf(s1 - m);
    wle[tx + 256] = __expf(s2 - m);
    wle[tx + 384] = __expf(s3 - m);
    __syncthreads();

    float acc = 0.f, Wc = 0.f;
    const f16* vb = v16 + (size_t)b * 512 * 256 + h;
    float* ob = out + (size_t)b * 512 * 256 + h;
    for (int t8 = 0; t8 < 64; ++t8) {
        float vv[8];
#pragma unroll
        for (int u = 0; u < 8; ++u) vv[u] = (float)vb[(size_t)(t8 * 8 + u) * 256];
#pragma unroll
        for (int u = 0; u < 8; ++u) {
            float wv = wle[t8 * 8 + u];
            Wc += wv;
            acc += wv * vv[u];
            ob[(size_t)(t8 * 8 + u) * 256] = acc * __builtin_amdgcn_rcpf(Wc);
        }
    }
}

// ---------------------------------------------------------------- launch
extern "C" void kernel_launch(void* const* d_in, const int* in_sizes, int n_in,
                              void* d_out, int out_size, void* d_ws, size_t ws_size,
                              hipStream_t stream) {
    const float* x     = (const float*)d_in[0];
    const float* Wp    = (const float*)d_in[1];
    const float* bp    = (const float*)d_in[2];
    const float* Wih_a = (const float*)d_in[3];
    const float* Whh_a = (const float*)d_in[4];
    const float* bih_a = (const float*)d_in[5];
    const float* bhh_a = (const float*)d_in[6];
    const float* Wih_b = (const float*)d_in[7];
    const float* Whh_b = (const float*)d_in[8];
    const float* bih_b = (const float*)d_in[9];
    const float* bhh_b = (const float*)d_in[10];
    const float* Wa    = (const float*)d_in[11];
    // d_in[12] = ba: dropped — softmax is shift-invariant.
    const float* Wb    = (const float*)d_in[13];
    const float* bb    = (const float*)d_in[14];
    float* out = (float*)d_out;

    char* ws = (char*)d_ws;
    size_t off = 0;
    auto take = [&](size_t bytes) -> void* {
        void* p = ws + off;
        off += (bytes + 255) & ~(size_t)255;
        return p;
    };
    f16* xp16     = (f16*)take(16777216ull * 2);      // xp [65536,256] f16      32 MiB
    char* xw_reg  = (char*)take(100663296ull * 2);    // xW cat [65536,1536] f16 192 MiB
    f16* xw_cat16 = (f16*)xw_reg;
    f16* v16      = (f16*)xw_reg;                     // alias (xW dead after rnn)
    float* scores = (float*)take(65536ull * 4);
    f16* wp16     = (f16*)take(32768ull * 2);
    f16* wih_cat  = (f16*)take(393216ull * 2);        // rows 0..767 = a, 768..1535 = b
    f16* whha16   = (f16*)take(196608ull * 2);
    f16* whhb16   = (f16*)take(196608ull * 2);
    f16* wb16     = (f16*)take(65536ull * 2);
    // d_out is [65536,256] f32 = 64 MiB. Lower 32 MiB: xb16 (f16). Upper 32 MiB:
    // xa16 (f16, only needed for the scores GEMV). attn overwrites d_out last.
    f16* xb16 = (f16*)d_out;
    f16* xa16 = (f16*)((char*)d_out + 33554432ull);
    (void)ws_size; (void)n_in; (void)in_sizes; (void)out_size;

    hipLaunchKernelGGL(cvt_weights_kernel, dim3(865), dim3(256), 0, stream,
                       Wp, Wih_a, Whh_a, Wih_b, Whh_b, Wb,
                       wp16, wih_cat, whha16, wih_cat + 768 * 256, whhb16, wb16);
    hipLaunchKernelGGL((gemm_kernel<128, 256, 0, true, (1 << 30)>), dim3(512, 2), dim3(256), 0, stream,
                       (const void*)x, wp16, bp, bp, xp16, (const f16*)nullptr);
    hipLaunchKernelGGL((gemm_kernel<256, 1536, 1, false, 768>), dim3(512, 12), dim3(256), 0, stream,
                       (const void*)xp16, wih_cat, bih_a, bih_b, xw_cat16, (const f16*)nullptr);
    hipLaunchKernelGGL(rnn_kernel, dim3(256), dim3(1024), 0, stream,
                       xw_cat16, whha16, whhb16, bhh_a, bhh_b, xa16, xb16);
    hipLaunchKernelGGL(scores_kernel, dim3(128), dim3(256), 0, stream, xa16, Wa, scores);
    hipLaunchKernelGGL((gemm_kernel<256, 256, 2, false, (1 << 30)>), dim3(512, 2), dim3(256), 0, stream,
                       (const void*)xb16, wb16, bb, bb, v16, xp16);
    hipLaunchKernelGGL(attn_kernel, dim3(128, 2), dim3(128), 0, stream, scores, v16, out);
}

// Round 4
// 967.441 us; speedup vs baseline: 1.1039x; 1.0380x over previous
//
#include <hip/hip_runtime.h>
#include <hip/hip_bf16.h>

typedef _Float16 f16;
typedef f16 f16x2 __attribute__((ext_vector_type(2)));
typedef f16 f16x8 __attribute__((ext_vector_type(8)));
typedef float f32x4 __attribute__((ext_vector_type(4)));

__device__ __forceinline__ float dot2acc(f16x2 a, f16x2 b, float c) {
    return __builtin_amdgcn_fdot2(a, b, c, false);
}
__device__ __forceinline__ float sigmoid_f(float x) {
    return __builtin_amdgcn_rcpf(1.f + __expf(-x));
}
__device__ __forceinline__ float tanh_f(float x) {
    return 1.f - 2.f * __builtin_amdgcn_rcpf(__expf(2.f * x) + 1.f);
}
// quad-lane DPP shuffle (pure VALU; keeps the LDS pipe free)
template <int CTRL>
__device__ __forceinline__ float dppx(float x) {
    return __builtin_bit_cast(float,
        __builtin_amdgcn_mov_dpp(__builtin_bit_cast(int, x), CTRL, 0xF, 0xF, true));
}
#define DPP_XOR1 0xB1  // quad_perm [1,0,3,2]
#define DPP_XOR2 0x4E  // quad_perm [2,3,0,1]

// ------------------------------------------------- fused weight f32->f16 convert
// Also builds bias_cat[1536] = bih + (bhh for the r,z thirds only): folding
// bhh_r/bhh_z into the xW GEMM bias lets the rnn gate skip 2 regs + 2 adds.
// Weight float4 count is 221184 (Wb = 256x256 = 16384 float4) — the original
// 221248 bound over-wrote 512B past wb16 (onto bias_cat). Bound corrected.
__global__ __launch_bounds__(256) void cvt_weights_kernel(
    const float* __restrict__ wp, const float* __restrict__ wia, const float* __restrict__ wha,
    const float* __restrict__ wib, const float* __restrict__ whb, const float* __restrict__ wb,
    const float* __restrict__ bia, const float* __restrict__ bha,
    const float* __restrict__ bib, const float* __restrict__ bhb,
    f16* __restrict__ o_wp, f16* __restrict__ o_wia, f16* __restrict__ o_wha,
    f16* __restrict__ o_wib, f16* __restrict__ o_whb, f16* __restrict__ o_wb,
    float* __restrict__ bias_cat)
{
    int i = blockIdx.x * 256 + threadIdx.x;
    if (i < 221184) {
        const float* s; f16* d; int off;
        if      (i < 8192)   { s = wp;  d = o_wp;  off = i; }
        else if (i < 57344)  { s = wia; d = o_wia; off = i - 8192; }
        else if (i < 106496) { s = wha; d = o_wha; off = i - 57344; }
        else if (i < 155648) { s = wib; d = o_wib; off = i - 106496; }
        else if (i < 204800) { s = whb; d = o_whb; off = i - 155648; }
        else                 { s = wb;  d = o_wb;  off = i - 204800; }
        float4 f = ((const float4*)s)[off];
        f16x2 p0; p0.x = (f16)f.x; p0.y = (f16)f.y;
        f16x2 p1; p1.x = (f16)f.z; p1.y = (f16)f.w;
        ((f16x2*)d)[off * 2]     = p0;
        ((f16x2*)d)[off * 2 + 1] = p1;
    } else if (i < 221568) {
        int c0 = (i - 221184) * 4;
        float4 v;
        float* pv = (float*)&v;
#pragma unroll
        for (int u = 0; u < 4; ++u) {
            int c = c0 + u;
            int g = c >= 768;
            int local = c - 768 * g;
            const float* bi = g ? bib : bia;
            const float* bh = g ? bhb : bha;
            float val = bi[local];
            if (local < 512) val += bh[local];
            pv[u] = val;
        }
        *(float4*)(bias_cat + c0) = v;
    }
}

// ---------------------------------------------------------------- MFMA GEMM
#define BM 128
#define BN 128
#define BKC 64
#define LPAD 8

template <int KT, int NOUT, int EPI, bool CVTA, int BSPLIT>
__global__ __launch_bounds__(256) void gemm_kernel(
    const void* __restrict__ Araw, const f16* __restrict__ B,
    const float* __restrict__ bias, const float* __restrict__ bias2,
    f16* __restrict__ out16, const f16* __restrict__ xp16)
{
    __shared__ __align__(16) f16 As[BM][BKC + LPAD];
    __shared__ __align__(16) f16 Bs[BN][BKC + LPAD];
    int tid = threadIdx.x;
    int m0 = blockIdx.x * BM, n0 = blockIdx.y * BN;
    int wave = tid >> 6, lane = tid & 63;
    int wm = (wave & 1) * 64, wn = (wave >> 1) * 64;
    int quad = lane >> 4, l16 = lane & 15;

    f32x4 acc[4][4] = {};

    for (int kc = 0; kc < KT / BKC; ++kc) {
        __syncthreads();
#pragma unroll
        for (int i = 0; i < 4; ++i) {
            int idx = i * 256 + tid;
            int row = idx >> 3, c8 = idx & 7;
            if (CVTA) {
                const float* A32 = (const float*)Araw;
                const float* src = A32 + (size_t)(m0 + row) * KT + kc * BKC + c8 * 8;
                float4 fa = *(const float4*)src;
                float4 fb = *(const float4*)(src + 4);
                f16x8 h8;
                h8[0] = (f16)fa.x; h8[1] = (f16)fa.y; h8[2] = (f16)fa.z; h8[3] = (f16)fa.w;
                h8[4] = (f16)fb.x; h8[5] = (f16)fb.y; h8[6] = (f16)fb.z; h8[7] = (f16)fb.w;
                *(f16x8*)&As[row][c8 * 8] = h8;
            } else {
                const f16* A16 = (const f16*)Araw;
                uint4 va = *(const uint4*)(A16 + (size_t)(m0 + row) * KT + kc * BKC + c8 * 8);
                *(uint4*)&As[row][c8 * 8] = va;
            }
            uint4 vb = *(const uint4*)(B + (size_t)(n0 + row) * KT + kc * BKC + c8 * 8);
            *(uint4*)&Bs[row][c8 * 8] = vb;
        }
        __syncthreads();
#pragma unroll
        for (int kk = 0; kk < 2; ++kk) {
            f16x8 af[4], bf[4];
#pragma unroll
            for (int i = 0; i < 4; ++i) {
                af[i] = *(const f16x8*)&As[wm + i * 16 + l16][kk * 32 + quad * 8];
                bf[i] = *(const f16x8*)&Bs[wn + i * 16 + l16][kk * 32 + quad * 8];
            }
#pragma unroll
            for (int mi = 0; mi < 4; ++mi)
#pragma unroll
                for (int ni = 0; ni < 4; ++ni)
                    acc[mi][ni] = __builtin_amdgcn_mfma_f32_16x16x32_f16(af[mi], bf[ni], acc[mi][ni], 0, 0, 0);
        }
    }

#pragma unroll
    for (int ni = 0; ni < 4; ++ni) {
        int col = n0 + wn + ni * 16 + l16;
        float bv = (col < BSPLIT) ? bias[col] : bias2[col - BSPLIT];
#pragma unroll
        for (int mi = 0; mi < 4; ++mi) {
#pragma unroll
            for (int r = 0; r < 4; ++r) {
                int row = m0 + wm + mi * 16 + quad * 4 + r;
                float val = acc[mi][ni][r] + bv;
                if (EPI == 2) {
                    float tb = tanh_f(val);
                    float xpv = (float)xp16[(size_t)row * NOUT + col];
                    out16[(size_t)row * NOUT + col] = (f16)(tb * xpv);
                } else {
                    out16[(size_t)row * NOUT + col] = (f16)val;
                }
            }
        }
    }
}

// ---------------------------------------------------------------- GRU recurrence
// 256 blocks (1/CU): blockIdx>>7 = GRU (0=a,1=b), &127 = batch. 1024 threads
// (16 waves = 4 waves/EU, 128-reg budget). Thread t = (j = t>>2, kp = t&3):
// owns rows {j, j+256, j+512} = r,z,n of the SAME h-index over k-chunk kp
// (64 h-elems) = 96 f16x2 weight regs. Total live demand must be <= 128 or the
// allocator parks w[] in AGPRs and every dot2 pays a v_accvgpr_read.
// ROUND-4 FIX: double-buffer toggle was `woff ^= 576` — 576 = 0x240 is NOT a
// single bit, and for j in [200,256) the base 576+x carries into bit 10, so the
// XOR produced addresses >= 1600 (outside h2): those h-writes were dropped every
// other step -> deterministic 3e-2 drift (identical rounds 2/3). Buffers now at
// 1024-byte stride; toggle XOR 1024 (single bit, offsets < 1024 -> always valid).
#define XWS 1536

__global__ __launch_bounds__(1024)
__attribute__((amdgpu_waves_per_eu(4, 4)))
void rnn_kernel(
    const f16* __restrict__ xw_cat,
    const f16* __restrict__ whha, const f16* __restrict__ whhb,
    const float* __restrict__ bhha, const float* __restrict__ bhhb,
    f16* __restrict__ xa16, f16* __restrict__ xb16)
{
    int g = blockIdx.x >> 7, b = blockIdx.x & 127;
    int t = threadIdx.x;
    int kp = t & 3;           // k-chunk: h-elems [kp*64, kp*64+64)
    int j  = t >> 2;          // h index 0..255

    const f16* whh = g ? whhb : whha;
    const float* bhh = g ? bhhb : bhha;
    const f16* xwp = xw_cat + (size_t)b * 512 * XWS + 768 * g;  // block-uniform
    f16* hop = (g ? xb16 : xa16) + (size_t)b * 512 * 256;       // block-uniform

    // weights: 3 rows (r,z,n of j) x 64 h-elems of chunk kp = 96 f16x2 = 96 VGPRs
    unsigned int w[96];
#pragma unroll
    for (int r = 0; r < 3; ++r) {
        const f16* src = whh + (size_t)(j + 256 * r) * 256 + kp * 64;
#pragma unroll
        for (int b8 = 0; b8 < 8; ++b8) {
            uint4 u = *(const uint4*)(src + b8 * 8);
            w[r * 32 + b8 * 4 + 0] = u.x;
            w[r * 32 + b8 * 4 + 1] = u.y;
            w[r * 32 + b8 * 4 + 2] = u.z;
            w[r * 32 + b8 * 4 + 3] = u.w;
        }
    }
#pragma unroll
    for (int i = 0; i < 96; ++i) asm volatile("" : "+v"(w[i]));  // pin in VGPRs

    float bn = bhh[j + 512];   // only the n-gate hidden bias survives folding

    // h double buffer: buffer q at byte q*1024; chunk c at byte offset c*144
    // within a buffer (144B stride -> per-wave broadcast hits disjoint banks)
    __shared__ __align__(16) f16 h2[2][512];
    char* lbase = (char*)&h2[0][0];
    unsigned roff = kp * 144;                                   // read base (buf0)
    unsigned woff = 1024 + (j >> 6) * 144 + (j & 63) * 2;       // write base (buf1)

    if (t < 256) h2[0][(t >> 6) * 72 + (t & 63)] = (f16)0.f;
    __syncthreads();

    float hprev = 0.f;
    // prefetch xW row for ts=0 (quad lanes load identical values -> coalesced)
    float xr = (float)xwp[j];
    float xz = (float)xwp[j + 256];
    float xn = (float)xwp[j + 512];
    for (int ts = 0; ts < 512; ++ts) {
        // issue next row's loads early; dot phase hides the latency.
        // (final iteration over-reads into the scores buffer - discarded)
        const f16* xwn = xwp + XWS;
        f16 nxr = xwn[j];
        f16 nxz = xwn[j + 256];
        f16 nxn = xwn[j + 512];

        // partial dots over chunk kp for rows j, j+256, j+512
        const f16* hb = (const f16*)(lbase + roff);
        float a0 = 0.f, a1 = 0.f, a2 = 0.f;
#pragma unroll
        for (int i8 = 0; i8 < 8; ++i8) {
            uint4 u = *(const uint4*)(hb + i8 * 8);
            f16x2 p0 = __builtin_bit_cast(f16x2, u.x);
            f16x2 p1 = __builtin_bit_cast(f16x2, u.y);
            f16x2 p2 = __builtin_bit_cast(f16x2, u.z);
            f16x2 p3 = __builtin_bit_cast(f16x2, u.w);
            int kc = i8 * 4;
            a0 = dot2acc(p0, __builtin_bit_cast(f16x2, w[kc + 0]), a0);
            a0 = dot2acc(p1, __builtin_bit_cast(f16x2, w[kc + 1]), a0);
            a0 = dot2acc(p2, __builtin_bit_cast(f16x2, w[kc + 2]), a0);
            a0 = dot2acc(p3, __builtin_bit_cast(f16x2, w[kc + 3]), a0);
            a1 = dot2acc(p0, __builtin_bit_cast(f16x2, w[32 + kc + 0]), a1);
            a1 = dot2acc(p1, __builtin_bit_cast(f16x2, w[32 + kc + 1]), a1);
            a1 = dot2acc(p2, __builtin_bit_cast(f16x2, w[32 + kc + 2]), a1);
            a1 = dot2acc(p3, __builtin_bit_cast(f16x2, w[32 + kc + 3]), a1);
            a2 = dot2acc(p0, __builtin_bit_cast(f16x2, w[64 + kc + 0]), a2);
            a2 = dot2acc(p1, __builtin_bit_cast(f16x2, w[64 + kc + 1]), a2);
            a2 = dot2acc(p2, __builtin_bit_cast(f16x2, w[64 + kc + 2]), a2);
            a2 = dot2acc(p3, __builtin_bit_cast(f16x2, w[64 + kc + 3]), a2);
        }
        // quad butterfly: all 4 lanes end with the full sums (bit-identical)
        a0 += dppx<DPP_XOR1>(a0); a0 += dppx<DPP_XOR2>(a0);
        a1 += dppx<DPP_XOR1>(a1); a1 += dppx<DPP_XOR2>(a1);
        a2 += dppx<DPP_XOR1>(a2); a2 += dppx<DPP_XOR2>(a2);

        // gate math, duplicated across the quad (no LDS exchange needed)
        float r = sigmoid_f(xr + a0);          // bhh_r folded into xW bias
        float z = sigmoid_f(xz + a1);          // bhh_z folded into xW bias
        float n = tanh_f(xn + r * (a2 + bn));
        float hnew = z * (hprev - n) + n;      // (1-z)*n + z*h
        hprev = hnew;
        xr = (float)nxr; xz = (float)nxz; xn = (float)nxn;
        xwp = xwn;

        f16 h16 = (f16)hnew;
        if (kp == 0) {
            *(f16*)(lbase + woff) = h16;
            hop[j] = h16;
        }
        hop += 256;
        __syncthreads();   // h(t+1) visible for next dot phase
        roff ^= 1024; woff ^= 1024;
    }
}

// ---------------------------------------------------------------- scores GEMV
// scores[b,t] = xa[b,t,:] . Wa   (deferred from the recurrence loop)
__global__ __launch_bounds__(256) void scores_kernel(
    const f16* __restrict__ xa16, const float* __restrict__ Wa, float* __restrict__ scores)
{
    int b = blockIdx.x;          // 128 blocks
    int t = threadIdx.x;         // 4 waves
    int wv = t >> 6, l = t & 63;
    float wa0 = Wa[l * 4 + 0];
    float wa1 = Wa[l * 4 + 1];
    float wa2 = Wa[l * 4 + 2];
    float wa3 = Wa[l * 4 + 3];
    const f16* base = xa16 + (size_t)b * 512 * 256;
    for (int row = wv; row < 512; row += 4) {
        const f16* rp = base + (size_t)row * 256 + l * 4;
        uint2 u = *(const uint2*)rp;
        f16x2 p0 = __builtin_bit_cast(f16x2, u.x);
        f16x2 p1 = __builtin_bit_cast(f16x2, u.y);
        float s = (float)p0.x * wa0 + (float)p0.y * wa1
                + (float)p1.x * wa2 + (float)p1.y * wa3;
#pragma unroll
        for (int off = 32; off; off >>= 1) s += __shfl_xor(s, off);
        if (l == 0) scores[b * 512 + row] = s;
    }
}

// ---------------------------------------------------------------- attention
// Running-scan prefix softmax. Grid (128 batches, 2 h-halves) x 128 threads.
__global__ __launch_bounds__(128) void attn_kernel(
    const float* __restrict__ scores, const f16* __restrict__ v16, float* __restrict__ out)
{
    int b = blockIdx.x, tx = threadIdx.x;
    int h = blockIdx.y * 128 + tx;
    __shared__ float wle[512];
    __shared__ float red[2];

    float s0 = scores[b * 512 + tx];
    float s1 = scores[b * 512 + 128 + tx];
    float s2 = scores[b * 512 + 256 + tx];
    float s3 = scores[b * 512 + 384 + tx];
    float m = fmaxf(fmaxf(s0, s1), fmaxf(s2, s3));
#pragma unroll
    for (int off = 32; off; off >>= 1) m = fmaxf(m, __shfl_down(m, off));
    if ((tx & 63) == 0) red[tx >> 6] = m;
    __syncthreads();
    m = fmaxf(red[0], red[1]);
    wle[tx]       = __expf(s0 - m);
    wle[tx + 128] = __expf(s1 - m);
    wle[tx + 256] = __expf(s2 - m);
    wle[tx + 384] = __expf(s3 - m);
    __syncthreads();

    float acc = 0.f, Wc = 0.f;
    const f16* vb = v16 + (size_t)b * 512 * 256 + h;
    float* ob = out + (size_t)b * 512 * 256 + h;
    for (int t8 = 0; t8 < 64; ++t8) {
        float vv[8];
#pragma unroll
        for (int u = 0; u < 8; ++u) vv[u] = (float)vb[(size_t)(t8 * 8 + u) * 256];
#pragma unroll
        for (int u = 0; u < 8; ++u) {
            float wv = wle[t8 * 8 + u];
            Wc += wv;
            acc += wv * vv[u];
            ob[(size_t)(t8 * 8 + u) * 256] = acc * __builtin_amdgcn_rcpf(Wc);
        }
    }
}

// ---------------------------------------------------------------- launch
extern "C" void kernel_launch(void* const* d_in, const int* in_sizes, int n_in,
                              void* d_out, int out_size, void* d_ws, size_t ws_size,
                              hipStream_t stream) {
    const float* x     = (const float*)d_in[0];
    const float* Wp    = (const float*)d_in[1];
    const float* bp    = (const float*)d_in[2];
    const float* Wih_a = (const float*)d_in[3];
    const float* Whh_a = (const float*)d_in[4];
    const float* bih_a = (const float*)d_in[5];
    const float* bhh_a = (const float*)d_in[6];
    const float* Wih_b = (const float*)d_in[7];
    const float* Whh_b = (const float*)d_in[8];
    const float* bih_b = (const float*)d_in[9];
    const float* bhh_b = (const float*)d_in[10];
    const float* Wa    = (const float*)d_in[11];
    // d_in[12] = ba: dropped — softmax is shift-invariant.
    const float* Wb    = (const float*)d_in[13];
    const float* bb    = (const float*)d_in[14];
    float* out = (float*)d_out;

    char* ws = (char*)d_ws;
    size_t off = 0;
    auto take = [&](size_t bytes) -> void* {
        void* p = ws + off;
        off += (bytes + 255) & ~(size_t)255;
        return p;
    };
    f16* xp16     = (f16*)take(16777216ull * 2);      // xp [65536,256] f16      32 MiB
    char* xw_reg  = (char*)take(100663296ull * 2);    // xW cat [65536,1536] f16 192 MiB
    f16* xw_cat16 = (f16*)xw_reg;
    f16* v16      = (f16*)xw_reg;                     // alias (xW dead after rnn)
    float* scores = (float*)take(65536ull * 4);
    f16* wp16     = (f16*)take(32768ull * 2);
    f16* wih_cat  = (f16*)take(393216ull * 2);        // rows 0..767 = a, 768..1535 = b
    f16* whha16   = (f16*)take(196608ull * 2);
    f16* whhb16   = (f16*)take(196608ull * 2);
    f16* wb16     = (f16*)take(65536ull * 2);
    float* bias_cat = (float*)take(1536ull * 4);      // bih + bhh(r,z thirds)
    // d_out is [65536,256] f32 = 64 MiB. Lower 32 MiB: xb16 (f16). Upper 32 MiB:
    // xa16 (f16, only needed for the scores GEMV). attn overwrites d_out last.
    f16* xb16 = (f16*)d_out;
    f16* xa16 = (f16*)((char*)d_out + 33554432ull);
    (void)ws_size; (void)n_in; (void)in_sizes; (void)out_size;

    hipLaunchKernelGGL(cvt_weights_kernel, dim3(866), dim3(256), 0, stream,
                       Wp, Wih_a, Whh_a, Wih_b, Whh_b, Wb,
                       bih_a, bhh_a, bih_b, bhh_b,
                       wp16, wih_cat, whha16, wih_cat + 768 * 256, whhb16, wb16,
                       bias_cat);
    hipLaunchKernelGGL((gemm_kernel<128, 256, 0, true, (1 << 30)>), dim3(512, 2), dim3(256), 0, stream,
                       (const void*)x, wp16, bp, bp, xp16, (const f16*)nullptr);
    hipLaunchKernelGGL((gemm_kernel<256, 1536, 1, false, (1 << 30)>), dim3(512, 12), dim3(256), 0, stream,
                       (const void*)xp16, wih_cat, bias_cat, bias_cat, xw_cat16, (const f16*)nullptr);
    hipLaunchKernelGGL(rnn_kernel, dim3(256), dim3(1024), 0, stream,
                       xw_cat16, whha16, whhb16, bhh_a, bhh_b, xa16, xb16);
    hipLaunchKernelGGL(scores_kernel, dim3(128), dim3(256), 0, stream, xa16, Wa, scores);
    hipLaunchKernelGGL((gemm_kernel<256, 256, 2, false, (1 << 30)>), dim3(512, 2), dim3(256), 0, stream,
                       (const void*)xb16, wb16, bb, bb, v16, xp16);
    hipLaunchKernelGGL(attn_kernel, dim3(128, 2), dim3(128), 0, stream, scores, v16, out);
}